// Round 4
// baseline (284.313 us; speedup 1.0000x reference)
//
#include <hip/hip_runtime.h>

// LongTermSpectralFlatness: x (32, 3000, 201, 2) fp32 -> flatness (32, 3000, 1) fp32
//
// Math (t >= 1):
//   s[t,f]     = (re^2+im^2) * scale[f] * hamm_sq_sum(25)/16000/10
//   welch[t,f] = mean(s[t-10..t-1, f])                  (cnt = max(min(t,10),1))
//   am[t,f]    = mean(welch[t-30..t-1, f]) + 1e-5
//   gm[t,f]    = exp(mean(log(welch[t-30..t-1,f]+1e-5)))   (the -eps+eps cancels!)
//   flat[t]    = log10(2) * sum_f ( log2(am) - mean(log2(welch+eps)) ),  flat[0] = 0
//
// R4: kernel est ~74us, ~3x stall ratio -> still latency-bound. Cut live VGPRs
// (drop l_ring: evicted log recomputed from w_ring bitwise-identically; drop
// sum refresh: pure sliding, drift << threshold) and per-frame issue cost
// (4-step butterfly with swizzle-only masks {16,8,4,2} -> 4 partials/frame;
// pointer-bump addressing instead of min-clamp muls; parity double-buffer
// instead of cur<-nxt mov shifts). __launch_bounds__(256,5): 5 waves/SIMD.

constexpr int TT = 3000;
constexpr int FF = 201;
constexpr int BB = 32;
constexpr int W1 = 10;
constexpr int W2 = 30;
constexpr int HALO = 40;   // W1 + W2
constexpr int LTILE = 60;  // output frames per tile
constexpr int NT = 50;     // 50 * 60 = 3000
#define EPSV 1e-5f
#define CSCALE (9.935f / 160000.0f)  // hamming_sq_sum(25)/16000/M
#define LOG10_2 0.3010299956639812f

// One 30-frame super-group = 6 unrolled groups of 5 frames.
// DYN: dynamic window counts + no lsum eviction (tile 0, t < 30).
// TERM: final supergroup — its g==5 prefetch is never consumed; re-read
// current group instead so addresses stay in-bounds for b=31, tile=49.
#define SUPERGROUP(DYN, TERM)                                                  \
  {                                                                            \
    _Pragma("unroll") for (int g = 0; g < 6; ++g) {                            \
      float2* cb = (g & 1) ? b1 : b0;  /* compile-time parity select */        \
      float2* nb = (g & 1) ? b0 : b1;                                          \
      const float2* pn = ((TERM) && g == 5) ? pf : (pf + 5 * FF);              \
      _Pragma("unroll") for (int j = 0; j < 5; ++j) nb[j] = pn[j * FF];        \
      float rr[5];                                                             \
      _Pragma("unroll") for (int j = 0; j < 5; ++j) {                          \
        const int fr = g * 5 + j;  /* frame within super-group (0..29) */      \
        const int t = t0 + m0 + fr;                                            \
        float inv10, inv30;                                                    \
        if (DYN) {                                                             \
          inv10 = 1.0f / (float)max(min(t, W1), 1);                            \
          inv30 = 1.0f / (float)max(min(t, W2), 1);                            \
        } else {                                                               \
          inv10 = 0.1f;                                                        \
          inv30 = (1.0f / 30.0f);                                              \
        }                                                                      \
        float welch = ssum * inv10;                                            \
        float lw = __log2f(welch + EPSV);                                      \
        float am = fmaf(wsum, inv30, EPSV);                                    \
        float la = __log2f(am);                                                \
        rr[j] = (la - lsum * inv30) * LOG10_2;                                 \
        float wold = w_ring[fr];                                               \
        if (DYN) lsum += lw; /* ring slot never pushed yet */                  \
        else     lsum += lw - __log2f(wold + EPSV); /* == lw added 30 ago */   \
        wsum += welch - wold;                                                  \
        w_ring[fr] = welch;                                                    \
        float sv = fmaf(cb[j].x, cb[j].x, cb[j].y * cb[j].y) * cs;             \
        ssum += sv - s_ring[fr % 10];                                          \
        s_ring[fr % 10] = sv;                                                  \
      }                                                                        \
      /* 4-step butterfly, swizzle-only masks; partials in lanes 0,1,32,33 */  \
      _Pragma("unroll") for (int off = 16; off >= 2; off >>= 1) {              \
        _Pragma("unroll") for (int j = 0; j < 5; ++j)                          \
            rr[j] += __shfl_xor(rr[j], off, 64);                               \
      }                                                                        \
      if ((lane & 30) == 0) {                                                  \
        const int p = (lane & 1) | ((lane >> 4) & 2);                          \
        _Pragma("unroll") for (int j = 0; j < 5; ++j)                          \
            ((float*)&part[wv][m0 + g * 5 + j])[p] = rr[j];                    \
      }                                                                        \
      pf = pn;                                                                 \
    }                                                                          \
    m0 += 30;                                                                  \
  }

__global__ __launch_bounds__(256, 5)
void ltsf_kernel(const float2* __restrict__ x, float* __restrict__ out) {
  const int tid = threadIdx.x;
  const int tile = blockIdx.x;
  const int b = blockIdx.y;
  const int t0 = tile * LTILE;
  const bool first = (tile == 0);
  const int tstart = first ? 0 : (t0 - HALO);
  const int lane = tid & 63;
  const int wv = tid >> 6;

  // freq bin; lanes >= 201 are zero-scale (their contrib is exactly 0 for t>=1)
  const int f = (tid < FF) ? tid : (FF - 1);
  float cs = (tid < FF) ? ((tid == 0 || tid == FF - 1) ? 1.0f : 2.0f) : 0.0f;
  cs *= CSCALE;

  const float2* xb = x + (size_t)b * TT * FF;

  __shared__ float4 part[4][LTILE];

  float s_ring[W1], w_ring[W2];
#pragma unroll
  for (int j = 0; j < W1; ++j) s_ring[j] = 0.f;
#pragma unroll
  for (int j = 0; j < W2; ++j) w_ring[j] = 0.f;
  float ssum = 0.f, wsum = 0.f, lsum = 0.f;

  float2 b0[5], b1[5];
  const float2* pf = xb + (size_t)tstart * FF + f;  // current group base

  // initial preload: frames tstart .. tstart+4 into b0
#pragma unroll
  for (int j = 0; j < 5; ++j) b0[j] = pf[j * FF];

  int m0 = 0;

  if (!first) {
    // ---- warm-up A: 2 groups, s-ring fill (stream frames 0..9) ----
#pragma unroll
    for (int g = 0; g < 2; ++g) {
      float2* cb = (g & 1) ? b1 : b0;
      float2* nb = (g & 1) ? b0 : b1;
      const float2* pn = pf + 5 * FF;
#pragma unroll
      for (int j = 0; j < 5; ++j) nb[j] = pn[j * FF];
#pragma unroll
      for (int j = 0; j < 5; ++j) {
        float sv = fmaf(cb[j].x, cb[j].x, cb[j].y * cb[j].y) * cs;
        ssum += sv;
        s_ring[g * 5 + j] = sv;
      }
      pf = pn;
    }
    // ---- warm-up B: 6 groups, welch/log window fill (stream frames 10..39) ----
#pragma unroll
    for (int g = 0; g < 6; ++g) {
      float2* cb = (g & 1) ? b1 : b0;
      float2* nb = (g & 1) ? b0 : b1;
      const float2* pn = pf + 5 * FF;
#pragma unroll
      for (int j = 0; j < 5; ++j) nb[j] = pn[j * FF];
#pragma unroll
      for (int j = 0; j < 5; ++j) {
        const int fr = g * 5 + j;
        float welch = ssum * 0.1f;  // full 10-window always here (t0 >= 60)
        float lw = __log2f(welch + EPSV);
        wsum += welch; w_ring[fr] = welch;
        lsum += lw;  // initial fill: no eviction
        float sv = fmaf(cb[j].x, cb[j].x, cb[j].y * cb[j].y) * cs;
        ssum += sv - s_ring[fr % 10];
        s_ring[fr % 10] = sv;
      }
      pf = pn;
    }
  }

  // ---- main: 2 super-groups of 30 output frames (LTILE = 60) ----
  if (first) {
    SUPERGROUP(true, false);   // t in [0,30): dynamic counts, no eviction
    SUPERGROUP(false, true);
  } else {
    SUPERGROUP(false, false);
    SUPERGROUP(false, true);
  }

  // ---- epilogue: sum the 16 partials (4 waves x 4 lanes) per frame ----
  __syncthreads();
  if (tid < LTILE) {
    float4 v0 = part[0][tid], v1 = part[1][tid];
    float4 v2 = part[2][tid], v3 = part[3][tid];
    float v = ((v0.x + v0.y) + (v0.z + v0.w)) + ((v1.x + v1.y) + (v1.z + v1.w)) +
              ((v2.x + v2.y) + (v2.z + v2.w)) + ((v3.x + v3.y) + (v3.z + v3.w));
    if (first && tid == 0) v = 0.f;  // reference forces frame 0 to exactly 0
    out[(size_t)b * TT + t0 + tid] = v;
  }
}

extern "C" void kernel_launch(void* const* d_in, const int* in_sizes, int n_in,
                              void* d_out, int out_size, void* d_ws, size_t ws_size,
                              hipStream_t stream) {
  const float2* x = (const float2*)d_in[0];
  float* out = (float*)d_out;
  dim3 grid(NT, BB);
  ltsf_kernel<<<grid, 256, 0, stream>>>(x, out);
}

// Round 5
// 225.584 us; speedup vs baseline: 1.2603x; 1.2603x over previous
//
#include <hip/hip_runtime.h>

// LongTermSpectralFlatness: x (32, 3000, 201, 2) fp32 -> flatness (32, 3000, 1) fp32
//
// Math (t >= 1):
//   s[t,f]     = (re^2+im^2) * scale[f] * hamm_sq_sum(25)/16000/10
//   welch[t,f] = mean(s[t-10..t-1, f])                  (cnt = max(min(t,10),1))
//   am[t,f]    = mean(welch[t-30..t-1, f]) + 1e-5
//   gm[t,f]    = exp(mean(log(welch[t-30..t-1,f]+1e-5)))   (the -eps+eps cancels!)
//   flat[t]    = log10(2) * sum_f ( log2(am) - mean(log2(welch+eps)) ),  flat[0] = 0
//
// R5: R4's structure was right but __launch_bounds__(256,5) made hipcc cap
// VGPRs at 48 (empirical: cap ~= 256/arg) -> 144 MB scratch spill, 140 us.
// Live set is ~85 VGPRs; (256,2) caps at 128 -> no spill, and HW occupancy
// is set by ACTUAL vgpr count (84-96 -> 4 waves/SIMD = 50%), not the arg.
// Keep: no l_ring (evict log recomputed from w_ring bitwise-identically),
// 4-step swizzle-only butterfly {16,8,4,2} -> 4 partials/frame, pointer-bump
// addressing, parity double-buffered 5-frame prefetch, grid 50x32 = 1600.

constexpr int TT = 3000;
constexpr int FF = 201;
constexpr int BB = 32;
constexpr int W1 = 10;
constexpr int W2 = 30;
constexpr int HALO = 40;   // W1 + W2
constexpr int LTILE = 60;  // output frames per tile
constexpr int NT = 50;     // 50 * 60 = 3000
#define EPSV 1e-5f
#define CSCALE (9.935f / 160000.0f)  // hamming_sq_sum(25)/16000/M
#define LOG10_2 0.3010299956639812f

// One 30-frame super-group = 6 unrolled groups of 5 frames.
// DYN: dynamic window counts + no lsum eviction (tile 0, t < 30).
// TERM: final supergroup — its g==5 prefetch is never consumed; re-read
// current group instead so addresses stay in-bounds for b=31, tile=49.
#define SUPERGROUP(DYN, TERM)                                                  \
  {                                                                            \
    _Pragma("unroll") for (int g = 0; g < 6; ++g) {                            \
      float2* cb = (g & 1) ? b1 : b0;  /* compile-time parity select */        \
      float2* nb = (g & 1) ? b0 : b1;                                          \
      const float2* pn = ((TERM) && g == 5) ? pf : (pf + 5 * FF);              \
      _Pragma("unroll") for (int j = 0; j < 5; ++j) nb[j] = pn[j * FF];        \
      float rr[5];                                                             \
      _Pragma("unroll") for (int j = 0; j < 5; ++j) {                          \
        const int fr = g * 5 + j;  /* frame within super-group (0..29) */      \
        const int t = t0 + m0 + fr;                                            \
        float inv10, inv30;                                                    \
        if (DYN) {                                                             \
          inv10 = 1.0f / (float)max(min(t, W1), 1);                            \
          inv30 = 1.0f / (float)max(min(t, W2), 1);                            \
        } else {                                                               \
          inv10 = 0.1f;                                                        \
          inv30 = (1.0f / 30.0f);                                              \
        }                                                                      \
        float welch = ssum * inv10;                                            \
        float lw = __log2f(welch + EPSV);                                      \
        float am = fmaf(wsum, inv30, EPSV);                                    \
        float la = __log2f(am);                                                \
        rr[j] = (la - lsum * inv30) * LOG10_2;                                 \
        float wold = w_ring[fr];                                               \
        if (DYN) lsum += lw; /* ring slot never pushed yet */                  \
        else     lsum += lw - __log2f(wold + EPSV); /* == lw added 30 ago */   \
        wsum += welch - wold;                                                  \
        w_ring[fr] = welch;                                                    \
        float sv = fmaf(cb[j].x, cb[j].x, cb[j].y * cb[j].y) * cs;             \
        ssum += sv - s_ring[fr % 10];                                          \
        s_ring[fr % 10] = sv;                                                  \
      }                                                                        \
      /* 4-step butterfly, swizzle-only masks; partials in lanes 0,1,32,33 */  \
      _Pragma("unroll") for (int off = 16; off >= 2; off >>= 1) {              \
        _Pragma("unroll") for (int j = 0; j < 5; ++j)                          \
            rr[j] += __shfl_xor(rr[j], off, 64);                               \
      }                                                                        \
      if ((lane & 30) == 0) {                                                  \
        const int p = (lane & 1) | ((lane >> 4) & 2);                          \
        _Pragma("unroll") for (int j = 0; j < 5; ++j)                          \
            ((float*)&part[wv][m0 + g * 5 + j])[p] = rr[j];                    \
      }                                                                        \
      pf = pn;                                                                 \
    }                                                                          \
    m0 += 30;                                                                  \
  }

__global__ __launch_bounds__(256, 2)
void ltsf_kernel(const float2* __restrict__ x, float* __restrict__ out) {
  const int tid = threadIdx.x;
  const int tile = blockIdx.x;
  const int b = blockIdx.y;
  const int t0 = tile * LTILE;
  const bool first = (tile == 0);
  const int tstart = first ? 0 : (t0 - HALO);
  const int lane = tid & 63;
  const int wv = tid >> 6;

  // freq bin; lanes >= 201 are zero-scale (their contrib is exactly 0 for t>=1)
  const int f = (tid < FF) ? tid : (FF - 1);
  float cs = (tid < FF) ? ((tid == 0 || tid == FF - 1) ? 1.0f : 2.0f) : 0.0f;
  cs *= CSCALE;

  const float2* xb = x + (size_t)b * TT * FF;

  __shared__ float4 part[4][LTILE];

  float s_ring[W1], w_ring[W2];
#pragma unroll
  for (int j = 0; j < W1; ++j) s_ring[j] = 0.f;
#pragma unroll
  for (int j = 0; j < W2; ++j) w_ring[j] = 0.f;
  float ssum = 0.f, wsum = 0.f, lsum = 0.f;

  float2 b0[5], b1[5];
  const float2* pf = xb + (size_t)tstart * FF + f;  // current group base

  // initial preload: frames tstart .. tstart+4 into b0
#pragma unroll
  for (int j = 0; j < 5; ++j) b0[j] = pf[j * FF];

  int m0 = 0;

  if (!first) {
    // ---- warm-up A: 2 groups, s-ring fill (stream frames 0..9) ----
#pragma unroll
    for (int g = 0; g < 2; ++g) {
      float2* cb = (g & 1) ? b1 : b0;
      float2* nb = (g & 1) ? b0 : b1;
      const float2* pn = pf + 5 * FF;
#pragma unroll
      for (int j = 0; j < 5; ++j) nb[j] = pn[j * FF];
#pragma unroll
      for (int j = 0; j < 5; ++j) {
        float sv = fmaf(cb[j].x, cb[j].x, cb[j].y * cb[j].y) * cs;
        ssum += sv;
        s_ring[g * 5 + j] = sv;
      }
      pf = pn;
    }
    // ---- warm-up B: 6 groups, welch/log window fill (stream frames 10..39) ----
#pragma unroll
    for (int g = 0; g < 6; ++g) {
      float2* cb = (g & 1) ? b1 : b0;
      float2* nb = (g & 1) ? b0 : b1;
      const float2* pn = pf + 5 * FF;
#pragma unroll
      for (int j = 0; j < 5; ++j) nb[j] = pn[j * FF];
#pragma unroll
      for (int j = 0; j < 5; ++j) {
        const int fr = g * 5 + j;
        float welch = ssum * 0.1f;  // full 10-window always here (t0 >= 60)
        float lw = __log2f(welch + EPSV);
        wsum += welch; w_ring[fr] = welch;
        lsum += lw;  // initial fill: no eviction
        float sv = fmaf(cb[j].x, cb[j].x, cb[j].y * cb[j].y) * cs;
        ssum += sv - s_ring[fr % 10];
        s_ring[fr % 10] = sv;
      }
      pf = pn;
    }
  }

  // ---- main: 2 super-groups of 30 output frames (LTILE = 60) ----
  if (first) {
    SUPERGROUP(true, false);   // t in [0,30): dynamic counts, no eviction
    SUPERGROUP(false, true);
  } else {
    SUPERGROUP(false, false);
    SUPERGROUP(false, true);
  }

  // ---- epilogue: sum the 16 partials (4 waves x 4 lanes) per frame ----
  __syncthreads();
  if (tid < LTILE) {
    float4 v0 = part[0][tid], v1 = part[1][tid];
    float4 v2 = part[2][tid], v3 = part[3][tid];
    float v = ((v0.x + v0.y) + (v0.z + v0.w)) + ((v1.x + v1.y) + (v1.z + v1.w)) +
              ((v2.x + v2.y) + (v2.z + v2.w)) + ((v3.x + v3.y) + (v3.z + v3.w));
    if (first && tid == 0) v = 0.f;  // reference forces frame 0 to exactly 0
    out[(size_t)b * TT + t0 + tid] = v;
  }
}

extern "C" void kernel_launch(void* const* d_in, const int* in_sizes, int n_in,
                              void* d_out, int out_size, void* d_ws, size_t ws_size,
                              hipStream_t stream) {
  const float2* x = (const float2*)d_in[0];
  float* out = (float*)d_out;
  dim3 grid(NT, BB);
  ltsf_kernel<<<grid, 256, 0, stream>>>(x, out);
}

// Round 7
// 223.084 us; speedup vs baseline: 1.2745x; 1.0112x over previous
//
#include <hip/hip_runtime.h>

// LongTermSpectralFlatness: x (32, 3000, 201, 2) fp32 -> flatness (32, 3000, 1) fp32
//
// Math (t >= 1):
//   s[t,f]     = (re^2+im^2) * scale[f] * hamm_sq_sum(25)/16000/10
//   welch[t,f] = mean(s[t-10..t-1, f])                  (cnt = max(min(t,10),1))
//   am[t,f]    = mean(welch[t-30..t-1, f]) + 1e-5
//   gm[t,f]    = exp(mean(log(welch[t-30..t-1,f]+1e-5)))   (the -eps+eps cancels!)
//   flat[t]    = log10(2) * sum_f ( log2(am) - mean(log2(welch+eps)) ),  flat[0] = 0
//
// R7 == R6 fixed (R6 was a compile error: '//' comment ate the macro
// line-continuation backslash). Theory unchanged:
// R5 == R3 total => not spill-bound; exposed global-load latency is the
// stall (prefetch distance ~360 cyc vs ~900 cyc cold HBM; halo re-reads cross
// XCDs). Fix 1: triple-buffered prefetch, distance = 2 groups (10 frames).
// Fix 2: grid transposed to (b, tile): linear = b + 32*tile, tile vs tile-1
// differ by 32 = 0 mod 8 -> same XCD -> halo hits local L2.
// Keep: no l_ring (evict log recomputed from w_ring bitwise-identically),
// 4-step swizzle-only butterfly {16,8,4,2}, pointer-bump addressing,
// __launch_bounds__(256,2) (VGPR cap 128; live ~95, no spill).

constexpr int TT = 3000;
constexpr int FF = 201;
constexpr int BB = 32;
constexpr int W1 = 10;
constexpr int W2 = 30;
constexpr int HALO = 40;   // W1 + W2
constexpr int LTILE = 60;  // output frames per tile
constexpr int NT = 50;     // 50 * 60 = 3000
#define EPSV 1e-5f
#define CSCALE (9.935f / 160000.0f)  // hamming_sq_sum(25)/16000/M
#define LOG10_2 0.3010299956639812f

#define BUFSEL(I) ((I) % 3 == 0 ? bufA : ((I) % 3 == 1 ? bufB : bufC))

/* Prefetch group GI+2 of the stream into its rotation slot. Terminal groups
   (GI+2 >= GTOT) re-read the last valid base: wasted but in-bounds. */
#define PF_GROUP(GI, GTOT)                                                     \
  {                                                                            \
    const float2* pn = ((GI) + 2 < (GTOT)) ? (pf2 + 5 * FF) : pf2;             \
    float2* nb = BUFSEL((GI) + 2);                                             \
    _Pragma("unroll") for (int j = 0; j < 5; ++j) nb[j] = pn[j * FF];          \
    pf2 = pn;                                                                  \
  }

/* Warm-up A: squares only, fill s_ring (stream groups 0..1, non-first tiles) */
#define WARMA_GROUP(GI)                                                        \
  {                                                                            \
    PF_GROUP(GI, 20);                                                          \
    float2* cb = BUFSEL(GI);                                                   \
    _Pragma("unroll") for (int j = 0; j < 5; ++j) {                            \
      float sv = fmaf(cb[j].x, cb[j].x, cb[j].y * cb[j].y) * cs;               \
      ssum += sv;                                                              \
      s_ring[(GI) * 5 + j] = sv;                                               \
    }                                                                          \
  }

/* Warm-up B: welch/log window fill, no eviction (stream groups 2..7).
   welch uses full 10-window always here (t0 >= 60). */
#define WARMB_GROUP(GI)                                                        \
  {                                                                            \
    PF_GROUP(GI, 20);                                                          \
    float2* cb = BUFSEL(GI);                                                   \
    _Pragma("unroll") for (int j = 0; j < 5; ++j) {                            \
      const int fr = ((GI) - 2) * 5 + j;                                       \
      float welch = ssum * 0.1f;                                               \
      float lw = __log2f(welch + EPSV);                                        \
      wsum += welch; w_ring[fr] = welch;                                       \
      lsum += lw;                                                              \
      float sv = fmaf(cb[j].x, cb[j].x, cb[j].y * cb[j].y) * cs;               \
      ssum += sv - s_ring[fr % 10];                                            \
      s_ring[fr % 10] = sv;                                                    \
    }                                                                          \
  }

/* Main: 5 output frames. GBASE = stream index of first main group.
   DYN: dynamic window counts + no lsum eviction (tile 0, t < 30).
   Non-DYN eviction recomputes the evicted log from w_ring: bitwise equal
   to the lw pushed 30 frames earlier. */
#define MAIN_GROUP(GI, GBASE, GTOT, DYN)                                       \
  {                                                                            \
    PF_GROUP(GI, GTOT);                                                        \
    float2* cb = BUFSEL(GI);                                                   \
    float rr[5];                                                               \
    _Pragma("unroll") for (int j = 0; j < 5; ++j) {                            \
      const int m = ((GI) - (GBASE)) * 5 + j;                                  \
      const int fr = m % 30;                                                   \
      const int t = t0 + m;                                                    \
      float inv10, inv30;                                                      \
      if (DYN) {                                                               \
        inv10 = 1.0f / (float)max(min(t, W1), 1);                              \
        inv30 = 1.0f / (float)max(min(t, W2), 1);                              \
      } else {                                                                 \
        inv10 = 0.1f;                                                          \
        inv30 = (1.0f / 30.0f);                                                \
      }                                                                        \
      float welch = ssum * inv10;                                              \
      float lw = __log2f(welch + EPSV);                                        \
      float am = fmaf(wsum, inv30, EPSV);                                      \
      float la = __log2f(am);                                                  \
      rr[j] = (la - lsum * inv30) * LOG10_2;                                   \
      float wold = w_ring[fr];                                                 \
      if (DYN) lsum += lw;                                                     \
      else     lsum += lw - __log2f(wold + EPSV);                              \
      wsum += welch - wold;                                                    \
      w_ring[fr] = welch;                                                      \
      float sv = fmaf(cb[j].x, cb[j].x, cb[j].y * cb[j].y) * cs;               \
      ssum += sv - s_ring[fr % 10];                                            \
      s_ring[fr % 10] = sv;                                                    \
    }                                                                          \
    /* 4-step butterfly, swizzle-only masks; partials in lanes 0,1,32,33 */    \
    _Pragma("unroll") for (int off = 16; off >= 2; off >>= 1) {                \
      _Pragma("unroll") for (int j = 0; j < 5; ++j)                            \
          rr[j] += __shfl_xor(rr[j], off, 64);                                 \
    }                                                                          \
    if ((lane & 30) == 0) {                                                    \
      const int p = (lane & 1) | ((lane >> 4) & 2);                            \
      _Pragma("unroll") for (int j = 0; j < 5; ++j)                            \
          ((float*)&part[wv][((GI) - (GBASE)) * 5 + j])[p] = rr[j];            \
    }                                                                          \
  }

__global__ __launch_bounds__(256, 2)
void ltsf_kernel(const float2* __restrict__ x, float* __restrict__ out) {
  const int tid = threadIdx.x;
  const int b = blockIdx.x;     // batch fastest: tile & tile-1 same XCD (%8)
  const int tile = blockIdx.y;
  const int t0 = tile * LTILE;
  const bool first = (tile == 0);
  const int tstart = first ? 0 : (t0 - HALO);
  const int lane = tid & 63;
  const int wv = tid >> 6;

  // freq bin; lanes >= 201 are zero-scale (their contrib is exactly 0 for t>=1)
  const int f = (tid < FF) ? tid : (FF - 1);
  float cs = (tid < FF) ? ((tid == 0 || tid == FF - 1) ? 1.0f : 2.0f) : 0.0f;
  cs *= CSCALE;

  const float2* xb = x + (size_t)b * TT * FF;

  __shared__ float4 part[4][LTILE];

  float s_ring[W1], w_ring[W2];
#pragma unroll
  for (int j = 0; j < W1; ++j) s_ring[j] = 0.f;
#pragma unroll
  for (int j = 0; j < W2; ++j) w_ring[j] = 0.f;
  float ssum = 0.f, wsum = 0.f, lsum = 0.f;

  float2 bufA[5], bufB[5], bufC[5];

  // preload stream groups 0 and 1; pf2 tracks the last-loaded group base
  const float2* p0 = xb + (size_t)tstart * FF + f;
#pragma unroll
  for (int j = 0; j < 5; ++j) bufA[j] = p0[j * FF];
  const float2* pf2 = p0 + 5 * FF;
#pragma unroll
  for (int j = 0; j < 5; ++j) bufB[j] = pf2[j * FF];

  if (!first) {
    // stream: 2 warm-A + 6 warm-B + 12 main = 20 groups (frames t0-40..t0+59)
    WARMA_GROUP(0)  WARMA_GROUP(1)
    WARMB_GROUP(2)  WARMB_GROUP(3)  WARMB_GROUP(4)
    WARMB_GROUP(5)  WARMB_GROUP(6)  WARMB_GROUP(7)
    MAIN_GROUP(8,  8, 20, false)  MAIN_GROUP(9,  8, 20, false)
    MAIN_GROUP(10, 8, 20, false)  MAIN_GROUP(11, 8, 20, false)
    MAIN_GROUP(12, 8, 20, false)  MAIN_GROUP(13, 8, 20, false)
    MAIN_GROUP(14, 8, 20, false)  MAIN_GROUP(15, 8, 20, false)
    MAIN_GROUP(16, 8, 20, false)  MAIN_GROUP(17, 8, 20, false)
    MAIN_GROUP(18, 8, 20, false)  MAIN_GROUP(19, 8, 20, false)
  } else {
    // stream: 12 main groups (frames 0..59); t<30 dynamic, no eviction
    MAIN_GROUP(0,  0, 12, true)   MAIN_GROUP(1,  0, 12, true)
    MAIN_GROUP(2,  0, 12, true)   MAIN_GROUP(3,  0, 12, true)
    MAIN_GROUP(4,  0, 12, true)   MAIN_GROUP(5,  0, 12, true)
    MAIN_GROUP(6,  0, 12, false)  MAIN_GROUP(7,  0, 12, false)
    MAIN_GROUP(8,  0, 12, false)  MAIN_GROUP(9,  0, 12, false)
    MAIN_GROUP(10, 0, 12, false)  MAIN_GROUP(11, 0, 12, false)
  }

  // ---- epilogue: sum the 16 partials (4 waves x 4 lanes) per frame ----
  __syncthreads();
  if (tid < LTILE) {
    float4 v0 = part[0][tid], v1 = part[1][tid];
    float4 v2 = part[2][tid], v3 = part[3][tid];
    float v = ((v0.x + v0.y) + (v0.z + v0.w)) + ((v1.x + v1.y) + (v1.z + v1.w)) +
              ((v2.x + v2.y) + (v2.z + v2.w)) + ((v3.x + v3.y) + (v3.z + v3.w));
    if (first && tid == 0) v = 0.f;  // reference forces frame 0 to exactly 0
    out[(size_t)b * TT + t0 + tid] = v;
  }
}

extern "C" void kernel_launch(void* const* d_in, const int* in_sizes, int n_in,
                              void* d_out, int out_size, void* d_ws, size_t ws_size,
                              hipStream_t stream) {
  const float2* x = (const float2*)d_in[0];
  float* out = (float*)d_out;
  dim3 grid(BB, NT);  // batch fastest: halo source tile lands on same XCD
  ltsf_kernel<<<grid, 256, 0, stream>>>(x, out);
}